// Round 1
// baseline (259.270 us; speedup 1.0000x reference)
//
#include <hip/hip_runtime.h>
#include <cstdint>
#include <cstddef>

// Problem constants (reference: B=4, T=4096, E=1024, M=E/2=512)
#define Tdim 4096
#define Bdim 4
#define Edim 1024
#define Mdim 512
#define EPSF 1e-6f

typedef __bf16 bf16x8 __attribute__((ext_vector_type(8)));
typedef float f32x4 __attribute__((ext_vector_type(4)));

// float -> bf16 bits, round-to-nearest-even
__device__ __forceinline__ unsigned short f2bf(float f) {
  union { float f; unsigned int u; } a; a.f = f;
  unsigned int r = a.u + 0x7fffu + ((a.u >> 16) & 1u);
  return (unsigned short)(r >> 16);
}

// bump kernel g(u) = exp(1 - 1/(1-u^2+eps)); the reference's u>=1-EPS clamp
// can never fire for j<=T-1 (u_max = 1 - 1/horizon), so it is omitted.
__device__ __forceinline__ float kernel_g(float dj, float inv_h) {
  float u = fminf(dj * inv_h, 1.0f - EPSF);
  return __expf(1.0f - 1.0f / (1.0f - u * u + EPSF));
}

typedef void __attribute__((address_space(1)))* gas1;
typedef void __attribute__((address_space(3)))* las3;
// async global->LDS, 16B per lane; LDS dest = wave-uniform base + lane*16
__device__ __forceinline__ void load_lds16(const void* g, void* l) {
  __builtin_amdgcn_global_load_lds((gas1)(g), (las3)(l), 16, 0, 0);
}

// ---------------- prep kernels ----------------

__global__ __launch_bounds__(256) void gate_kernel(const float* __restrict__ graw,
                                                   float* __restrict__ gate) {
  const int m = blockIdx.x * 256 + threadIdx.x;
  if (m < Mdim) {
    const float v = graw[m];
    gate[m] = fmaxf(v, 0.0f) + log1pf(__expf(-fabsf(v)));  // stable softplus
  }
}

__global__ __launch_bounds__(256) void rowsum_kernel(float* __restrict__ inv_rowsum) {
  const int i = blockIdx.x;
  const int tid = threadIdx.x;
  const float inv_h = 1.0f / (float)(Tdim - i);
  float s = 0.0f;
  for (int j = i + tid; j < Tdim; j += 256)
    s += kernel_g((float)(j - i), inv_h);
#pragma unroll
  for (int off = 32; off; off >>= 1) s += __shfl_down(s, off);
  __shared__ float red[4];
  if ((tid & 63) == 0) red[tid >> 6] = s;
  __syncthreads();
  if (tid == 0) inv_rowsum[i] = 1.0f / (red[0] + red[1] + red[2] + red[3]);
}

// K matrix, normalized, bf16, zeros below diagonal. grid (T/2048? no): (2, T)
__global__ __launch_bounds__(256) void kgen_kernel(const float* __restrict__ inv_rowsum,
                                                   unsigned short* __restrict__ Kmat) {
  const int i = blockIdx.y;
  const int j0 = (blockIdx.x * 256 + threadIdx.x) * 8;
  union { unsigned short u[8]; uint4 v; } pk;
  if (j0 + 7 < i) {
    pk.v = make_uint4(0u, 0u, 0u, 0u);
  } else {
    const float inv_h = 1.0f / (float)(Tdim - i);
    const float inv_s = inv_rowsum[i];
#pragma unroll
    for (int t = 0; t < 8; ++t) {
      const int j = j0 + t;
      float r = 0.0f;
      if (j >= i) r = kernel_g((float)(j - i), inv_h) * inv_s;
      pk.u[t] = f2bf(r);
    }
  }
  *reinterpret_cast<uint4*>(&Kmat[(size_t)i * Tdim + j0]) = pk.v;
}

// XcT[b][m][j] = bf16(x[b][j][2m])  (transposed so GEMM B-frag is k-contiguous)
// tile: 64 j x 32 m per block. grid (T/64, M/32, B)
__global__ __launch_bounds__(256) void extract_kernel(const float* __restrict__ x,
                                                      unsigned short* __restrict__ XcT) {
  __shared__ unsigned short Ls[32][68];
  const int j0 = blockIdx.x * 64;
  const int m0 = blockIdx.y * 32;
  const int b  = blockIdx.z;
  const int tid = threadIdx.x;
  const int q = tid & 15;        // float4 chunk along e
  const int jbase = tid >> 4;    // 0..15
#pragma unroll
  for (int it = 0; it < 4; ++it) {
    const int jj = jbase + it * 16;
    const size_t off = ((size_t)(b * Tdim + j0 + jj)) * Edim + 2 * m0 + 4 * q;
    const float4 v = *reinterpret_cast<const float4*>(&x[off]);
    Ls[2 * q][jj]     = f2bf(v.x);   // even channel of m0+2q
    Ls[2 * q + 1][jj] = f2bf(v.z);   // even channel of m0+2q+1
  }
  __syncthreads();
  const int ch = tid & 15;
  const int mb = tid >> 4;
#pragma unroll
  for (int it = 0; it < 2; ++it) {
    const int m = mb + it * 16;
    ushort4 uv;
    uv.x = Ls[m][4 * ch];
    uv.y = Ls[m][4 * ch + 1];
    uv.z = Ls[m][4 * ch + 2];
    uv.w = Ls[m][4 * ch + 3];
    *reinterpret_cast<ushort4*>(
        &XcT[((size_t)(b * Mdim + m0 + m)) * Tdim + j0 + 4 * ch]) = uv;
  }
}

// ---------------- main GEMM: phi[b,i,m] = sum_j K[i,j] * Xc[b,j,m] ----------------
// C-tile 128(i) x 128(m), BK=64, 4 waves, each wave 64x64 as 4x4 frags of 16x16x32.
// K-loop starts at j0 = i0 (triangular skip). Epilogue fuses even-channel passthrough.
__global__ __launch_bounds__(256) void gemm_kernel(
    const unsigned short* __restrict__ Kmat,
    const unsigned short* __restrict__ XcT,
    const float* __restrict__ x,
    const float* __restrict__ gate,
    float* __restrict__ out) {
  const int i0 = blockIdx.x * 128;   // heavy tiles (small i0) dispatched first
  const int m0 = blockIdx.y * 128;
  const int b  = blockIdx.z;
  __shared__ unsigned short As[128 * 64];  // K rows i0..i0+127, cols j0..j0+63
  __shared__ unsigned short Bs[128 * 64];  // XcT rows m0..m0+127, cols j0..j0+63
  const int tid = threadIdx.x;
  const int w = tid >> 6;
  const int l = tid & 63;
  f32x4 acc[4][4] = {};
  const int wr = w >> 1, wc = w & 1;
  const unsigned short* Arow = Kmat + (size_t)i0 * Tdim;
  const unsigned short* Brow = XcT + ((size_t)b * Mdim + m0) * Tdim;
  const int srow = l >> 3;           // 0..7 rows within 8-row group
  const int scol = (l & 7) * 8;      // 8 bf16 = 16B per lane

  for (int j0 = i0; j0 < Tdim; j0 += 64) {
#pragma unroll
    for (int t = 0; t < 4; ++t) {
      const int rr = (w * 4 + t) * 8 + srow;
      load_lds16(Arow + (size_t)rr * Tdim + (j0 + scol), &As[(w * 4 + t) * 512]);
      load_lds16(Brow + (size_t)rr * Tdim + (j0 + scol), &Bs[(w * 4 + t) * 512]);
    }
    __syncthreads();  // drains vmcnt (global_load_lds) per gfx950 semantics
    const int lr16 = l & 15;
    const int kq = (l >> 4) * 8;
#pragma unroll
    for (int kk = 0; kk < 2; ++kk) {
      bf16x8 af[4], bfr[4];
      const int k0 = kk * 32 + kq;
#pragma unroll
      for (int r = 0; r < 4; ++r)
        af[r] = *reinterpret_cast<const bf16x8*>(&As[(wr * 64 + r * 16 + lr16) * 64 + k0]);
#pragma unroll
      for (int c = 0; c < 4; ++c)
        bfr[c] = *reinterpret_cast<const bf16x8*>(&Bs[(wc * 64 + c * 16 + lr16) * 64 + k0]);
#pragma unroll
      for (int r = 0; r < 4; ++r)
#pragma unroll
        for (int c = 0; c < 4; ++c)
          acc[r][c] = __builtin_amdgcn_mfma_f32_16x16x32_bf16(af[r], bfr[c], acc[r][c], 0, 0, 0);
    }
    __syncthreads();
  }

  // epilogue: C/D layout col=lane&15 (m), row=(lane>>4)*4+reg (i)
  const int lr = l & 15;
  const int lq = l >> 4;
#pragma unroll
  for (int r = 0; r < 4; ++r) {
    const int i = i0 + wr * 64 + r * 16 + lq * 4;
#pragma unroll
    for (int c = 0; c < 4; ++c) {
      const int m = m0 + wc * 64 + c * 16 + lr;
      const float gm = gate[m];
#pragma unroll
      for (int v = 0; v < 4; ++v) {
        const size_t o = ((size_t)(b * Tdim + i + v)) * Edim + 2 * m;
        const float2 xv = *reinterpret_cast<const float2*>(&x[o]);
        float2 res;
        res.x = xv.x;                 // even channel: exact fp32 passthrough
        res.y = acc[r][c][v] * gm;    // odd channel: phi * gate
        *reinterpret_cast<float2*>(&out[o]) = res;
      }
    }
  }
}

// ---------------- slow-but-correct fallback (only if ws too small) ----------------
__global__ __launch_bounds__(256) void fallback_kernel(const float* __restrict__ x,
                                                       const float* __restrict__ graw,
                                                       float* __restrict__ out) {
  const int i = blockIdx.x, b = blockIdx.y, tid = threadIdx.x;
  const float inv_h = 1.0f / (float)(Tdim - i);
  float s = 0.0f;
  for (int j = i + tid; j < Tdim; j += 256)
    s += kernel_g((float)(j - i), inv_h);
#pragma unroll
  for (int off = 32; off; off >>= 1) s += __shfl_down(s, off);
  __shared__ float red[4];
  __shared__ float sinv_sh;
  if ((tid & 63) == 0) red[tid >> 6] = s;
  __syncthreads();
  if (tid == 0) sinv_sh = 1.0f / (red[0] + red[1] + red[2] + red[3]);
  __syncthreads();
  const float sinv = sinv_sh;
  const float* xb = x + (size_t)b * Tdim * Edim;
  float a0 = 0.0f, a1 = 0.0f;
  const int m0 = tid, m1 = tid + 256;
  for (int j = i; j < Tdim; ++j) {
    const float wgt = kernel_g((float)(j - i), inv_h);
    const float* xr = xb + (size_t)j * Edim;
    a0 += wgt * xr[2 * m0];
    a1 += wgt * xr[2 * m1];
  }
  const float v0 = graw[m0], v1 = graw[m1];
  const float g0 = fmaxf(v0, 0.0f) + log1pf(__expf(-fabsf(v0)));
  const float g1 = fmaxf(v1, 0.0f) + log1pf(__expf(-fabsf(v1)));
  const size_t o = ((size_t)(b * Tdim + i)) * Edim;
  const float* xi = xb + (size_t)i * Edim;
  out[o + 2 * m0]     = xi[2 * m0];
  out[o + 2 * m0 + 1] = a0 * sinv * g0;
  out[o + 2 * m1]     = xi[2 * m1];
  out[o + 2 * m1 + 1] = a1 * sinv * g1;
}

extern "C" void kernel_launch(void* const* d_in, const int* in_sizes, int n_in,
                              void* d_out, int out_size, void* d_ws, size_t ws_size,
                              hipStream_t stream) {
  const float* x = (const float*)d_in[0];
  // d_in[1] is the triu mask: always upper-triangular by construction; folded analytically.
  const float* gate_raw = (const float*)d_in[2];
  float* out = (float*)d_out;

  const size_t XcT_bytes = (size_t)Bdim * Mdim * Tdim * 2;  // 16 MiB
  const size_t K_bytes   = (size_t)Tdim * Tdim * 2;         // 32 MiB
  const size_t need = XcT_bytes + K_bytes + (size_t)(Tdim + Mdim) * sizeof(float);

  if (ws_size < need) {
    fallback_kernel<<<dim3(Tdim, Bdim), 256, 0, stream>>>(x, gate_raw, out);
    return;
  }

  char* ws = (char*)d_ws;
  unsigned short* XcT  = (unsigned short*)ws;
  unsigned short* Kmat = (unsigned short*)(ws + XcT_bytes);
  float* inv_rowsum    = (float*)(ws + XcT_bytes + K_bytes);
  float* gate          = inv_rowsum + Tdim;

  gate_kernel<<<dim3((Mdim + 255) / 256), 256, 0, stream>>>(gate_raw, gate);
  rowsum_kernel<<<dim3(Tdim), 256, 0, stream>>>(inv_rowsum);
  kgen_kernel<<<dim3(Tdim / (256 * 8), Tdim), 256, 0, stream>>>(inv_rowsum, Kmat);
  extract_kernel<<<dim3(Tdim / 64, Mdim / 32, Bdim), 256, 0, stream>>>(x, XcT);
  gemm_kernel<<<dim3(Tdim / 128, Mdim / 128, Bdim), 256, 0, stream>>>(Kmat, XcT, x, gate, out);
}